// Round 7
// baseline (749.456 us; speedup 1.0000x reference)
//
#include <hip/hip_runtime.h>
#include <hip/hip_bf16.h>

#define NN 2048
#define BB 8
#define NC 64

typedef __bf16 bf16_8 __attribute__((ext_vector_type(8)));
typedef __bf16 bf16_4 __attribute__((ext_vector_type(4)));
typedef float f32x16 __attribute__((ext_vector_type(16)));

__device__ __forceinline__ void gll16(const void* g, void* l) {
  __builtin_amdgcn_global_load_lds((const __attribute__((address_space(1))) void*)g,
                                   (__attribute__((address_space(3))) void*)l,
                                   16, 0, 0);
}

// fp32 -> bf16 convert + transpose, 16B/lane global reads.
__global__ __launch_bounds__(256)
void k_convert(const float* __restrict__ A, __bf16* __restrict__ Ab, __bf16* __restrict__ At) {
  __shared__ __bf16 tile[64][65];
  int b = blockIdx.z;
  const float* Asrc = A + (size_t)b * NN * NN;
  __bf16* Abd = Ab + (size_t)b * NN * NN;
  __bf16* Atd = At + (size_t)b * NN * NN;
  int r0 = blockIdx.y * 64, c0 = blockIdx.x * 64;
  int row = threadIdx.x >> 4;          // 0..15
  int col4 = (threadIdx.x & 15) * 4;   // 0..60
#pragma unroll
  for (int rr = 0; rr < 64; rr += 16) {
    float4 v = *(const float4*)&Asrc[(size_t)(r0 + row + rr) * NN + c0 + col4];
    bf16_4 hv;
    hv[0] = (__bf16)v.x; hv[1] = (__bf16)v.y; hv[2] = (__bf16)v.z; hv[3] = (__bf16)v.w;
    *(bf16_4*)&Abd[(size_t)(r0 + row + rr) * NN + c0 + col4] = hv;
    tile[row + rr][col4 + 0] = hv[0];
    tile[row + rr][col4 + 1] = hv[1];
    tile[row + rr][col4 + 2] = hv[2];
    tile[row + rr][col4 + 3] = hv[3];
  }
  __syncthreads();
  int row2 = threadIdx.x >> 3;         // 0..31
  int col8 = (threadIdx.x & 7) * 8;    // 0..56
#pragma unroll
  for (int rr = 0; rr < 64; rr += 32) {
    bf16_8 v;
#pragma unroll
    for (int j = 0; j < 8; ++j) v[j] = tile[col8 + j][row2 + rr];
    *(bf16_8*)&Atd[(size_t)(c0 + row2 + rr) * NN + r0 + col8] = v;
  }
}

// C[m,n] = sum_k P[m,k]*Q[n,k] for one batch. Block 256(M)x128(N), BK=64,
// 32x32x16 MFMA, 4 waves each 128x64 (4x2 frags), XOR chunk swizzle.
// Optional dual-write epilogue (Ct != null): restage C^T through dead LDS.
__device__ __forceinline__
void gemm_body(const __bf16* __restrict__ Pb, const __bf16* __restrict__ Qb,
               __bf16* __restrict__ Cb, __bf16* __restrict__ Ctb,
               __bf16* smem, int tmBlk, int tnBlk) {
  __bf16 (*As)[64] = (__bf16(*)[64])smem;            // 256 rows (32 KB)
  __bf16 (*Bs)[64] = (__bf16(*)[64])(smem + 16384);  // 128 rows (16 KB)
  int tid = threadIdx.x;
  int wave = tid >> 6;
  int lane = tid & 63;
  int tm = tmBlk * 256;
  int tn = tnBlk * 128;
  int wm = (wave >> 1) * 128;   // rows [wm, wm+128): 4 frags
  int wn = (wave & 1) * 64;     // cols [wn, wn+64): 2 frags

  // staging: row r's 16B-chunk c lands at LDS position c ^ (r&7)
  int srow = lane >> 3;
  int sc = (lane & 7) ^ srow;
  int arowA = wave * 64;
  int arowB = wave * 32;
  const __bf16* pA = Pb + (size_t)(tm + arowA + srow) * NN + sc * 8;
  const __bf16* pB = Qb + (size_t)(tn + arowB + srow) * NN + sc * 8;

  int am = lane & 31;   // frag row (m or n) within 32
  int ah = lane >> 5;   // k-half

  f32x16 acc[4][2] = {};

  for (int k0 = 0; k0 < NN; k0 += 64) {
#pragma unroll
    for (int g = 0; g < 8; ++g)
      gll16(pA + (size_t)(g * 8) * NN + k0, &As[arowA + g * 8][0]);
#pragma unroll
    for (int g = 0; g < 4; ++g)
      gll16(pB + (size_t)(g * 8) * NN + k0, &Bs[arowB + g * 8][0]);
    __syncthreads();
#pragma unroll
    for (int ks = 0; ks < 4; ++ks) {
      int cch = ks * 2 + ah;
      bf16_8 af[4], bf2[2];
#pragma unroll
      for (int i = 0; i < 4; ++i) {
        int ra = wm + i * 32 + am;
        af[i] = *(const bf16_8*)&As[ra][(cch ^ (ra & 7)) * 8];
      }
#pragma unroll
      for (int i = 0; i < 2; ++i) {
        int rb2 = wn + i * 32 + am;
        bf2[i] = *(const bf16_8*)&Bs[rb2][(cch ^ (rb2 & 7)) * 8];
      }
#pragma unroll
      for (int im = 0; im < 4; ++im)
#pragma unroll
        for (int in = 0; in < 2; ++in)
          acc[im][in] = __builtin_amdgcn_mfma_f32_32x32x16_bf16(af[im], bf2[in], acc[im][in], 0, 0, 0);
    }
    __syncthreads();
  }

  // C/D layout (32x32): col = lane&31, row = (reg&3) + 8*(reg>>2) + 4*(lane>>5)
  int cc = lane & 31;
  int rq = (lane >> 5) * 4;
#pragma unroll
  for (int im = 0; im < 4; ++im)
#pragma unroll
    for (int in = 0; in < 2; ++in)
#pragma unroll
      for (int reg = 0; reg < 16; ++reg) {
        int row = (reg & 3) + 8 * (reg >> 2) + rq;
        Cb[(size_t)(tm + wm + im * 32 + row) * NN + (tn + wn + in * 32 + cc)] =
            (__bf16)acc[im][in][reg];
      }

  if (Ctb != nullptr) {
    __bf16 (*Tt)[258] = (__bf16(*)[258])smem;  // 64 x 258 = 33 KB < 48 KB
#pragma unroll
    for (int ch = 0; ch < 2; ++ch) {
      __syncthreads();  // smem free (K-loop / previous chunk done)
      if ((wave & 1) == ch) {
#pragma unroll
        for (int im = 0; im < 4; ++im)
#pragma unroll
          for (int in = 0; in < 2; ++in)
#pragma unroll
            for (int g = 0; g < 4; ++g) {
              bf16_4 v;
#pragma unroll
              for (int r = 0; r < 4; ++r) v[r] = (__bf16)acc[im][in][g * 4 + r];
              *(bf16_4*)&Tt[in * 32 + cc][wm + im * 32 + rq + 8 * g] = v;
            }
      }
      __syncthreads();
#pragma unroll
      for (int p = 0; p < 4; ++p) {
        int trow = p * 16 + (tid >> 4);
        int tcol = (tid & 15) * 16;
        bf16_8 v0 = *(const bf16_8*)&Tt[trow][tcol];
        bf16_8 v1 = *(const bf16_8*)&Tt[trow][tcol + 8];
        size_t gr = (size_t)(tn + ch * 64 + trow) * NN + tm + tcol;
        *(bf16_8*)&Ctb[gr] = v0;
        *(bf16_8*)&Ctb[gr + 8] = v1;
      }
    }
  }
}

// G1: A2 = A @ A (dual-write A2, A2t)
__global__ __launch_bounds__(256, 3)
void k_gemm1(const __bf16* __restrict__ Ab, const __bf16* __restrict__ At,
             __bf16* __restrict__ A2, __bf16* __restrict__ A2t) {
  __shared__ __align__(16) __bf16 smem[24576];  // 48 KB
  size_t mb = (size_t)blockIdx.z * NN * NN;
  gemm_body(Ab + mb, At + mb, A2 + mb, A2t + mb, smem, blockIdx.y, blockIdx.x);
}

// G2+G3 merged: z<8 -> A3t = At @ A2^T (single write); z>=8 -> A4 = A2 @ A2
// (dual-write A4, A4t). Both jobs depend only on G1 outputs, mutually
// independent -> one dispatch halves tail/drain overhead.
__global__ __launch_bounds__(256, 3)
void k_gemm23(const __bf16* __restrict__ At, const __bf16* __restrict__ A2,
              const __bf16* __restrict__ A2t,
              __bf16* __restrict__ A3t, __bf16* __restrict__ A4,
              __bf16* __restrict__ A4t) {
  __shared__ __align__(16) __bf16 smem[24576];  // 48 KB
  int job = blockIdx.z >> 3;
  size_t mb = (size_t)(blockIdx.z & 7) * NN * NN;
  if (job == 0)
    gemm_body(At + mb, A2 + mb, A3t + mb, nullptr, smem, blockIdx.y, blockIdx.x);
  else
    gemm_body(A2 + mb, A2t + mb, A4 + mb, A4t + mb, smem, blockIdx.y, blockIdx.x);
}

// One wave per row n. d1..d4 are free diagonal reads (d2=A2[n,n], d3=A3t[n,n],
// d4=A4[n,n]); only d5..d8 need row-dots (all against row_n(A4)).
__global__ __launch_bounds__(256)
void k_reduce(const float* __restrict__ A, const float* __restrict__ h,
              const __bf16* __restrict__ At, const __bf16* __restrict__ A2,
              const __bf16* __restrict__ A2t, const __bf16* __restrict__ A3t,
              const __bf16* __restrict__ A4, const __bf16* __restrict__ A4t,
              float* __restrict__ out) {
  int b = blockIdx.y;
  int wave = threadIdx.x >> 6, lane = threadIdx.x & 63;
  int n = blockIdx.x * 4 + wave;
  size_t mb = (size_t)b * NN * NN;
  size_t rb = mb + (size_t)n * NN;
  float d5 = 0, d6 = 0, d7 = 0, d8 = 0;
  for (int c = 0; c < NN; c += 512) {
    int k = c + lane * 8;
    bf16_8 va4  = *(const bf16_8*)(A4 + rb + k);
    bf16_8 vat  = *(const bf16_8*)(At + rb + k);
    bf16_8 va2t = *(const bf16_8*)(A2t + rb + k);
    bf16_8 va3t = *(const bf16_8*)(A3t + rb + k);
    bf16_8 va4t = *(const bf16_8*)(A4t + rb + k);
#pragma unroll
    for (int j = 0; j < 8; ++j) {
      float f4 = (float)va4[j];
      d5 += f4 * (float)vat[j];
      d6 += f4 * (float)va2t[j];
      d7 += f4 * (float)va3t[j];
      d8 += f4 * (float)va4t[j];
    }
  }
#pragma unroll
  for (int off = 32; off > 0; off >>= 1) {
    d5 += __shfl_xor(d5, off);
    d6 += __shfl_xor(d6, off);
    d7 += __shfl_xor(d7, off);
    d8 += __shfl_xor(d8, off);
  }
  float d1 = A[mb + (size_t)n * NN + n];
  float d2 = (float)A2[rb + n];
  float d3 = (float)A3t[rb + n];
  float d4 = (float)A4[rb + n];
  // lane == channel (NC=64)
  float r = h[lane] + h[64 + lane] * d1 + h[128 + lane] * d2 + h[192 + lane] * d3 +
            h[256 + lane] * d4 + h[320 + lane] * d5 + h[384 + lane] * d6 +
            h[448 + lane] * d7 + h[512 + lane] * d8;
  out[((size_t)b * NN + n) * NC + lane] = r;
}

extern "C" void kernel_launch(void* const* d_in, const int* in_sizes, int n_in,
                              void* d_out, int out_size, void* d_ws, size_t ws_size,
                              hipStream_t stream) {
  const float* A = (const float*)d_in[0];
  const float* h = (const float*)d_in[1];
  float* out = (float*)d_out;

  size_t elems = (size_t)BB * NN * NN;  // 64 MiB per bf16 buffer
  __bf16* Ab  = (__bf16*)d_ws;
  __bf16* At  = Ab + elems;
  __bf16* A2  = At + elems;
  __bf16* A2t = A2 + elems;
  __bf16* A3t = A2t + elems;
  __bf16* A4  = A3t + elems;
  __bf16* A4t = Ab;  // alias: Ab dead after G1 (total ws: 6 x 64 MiB)

  dim3 bl(256);
  // A -> bf16 + transpose
  k_convert<<<dim3(32, 32, BB), bl, 0, stream>>>(A, Ab, At);
  // A2 = A @ A  (dual-write)
  k_gemm1<<<dim3(16, 8, BB), bl, 0, stream>>>(Ab, At, A2, A2t);
  // A3t = (A^3)^T and A4 = A2 @ A2 (+A4t) in one dispatch
  k_gemm23<<<dim3(16, 8, 2 * BB), bl, 0, stream>>>(At, A2, A2t, A3t, A4, A4t);
  // diagonals + channel combine
  k_reduce<<<dim3(NN / 4, BB), bl, 0, stream>>>(A, h, At, A2, A2t, A3t, A4, A4t, out);
}

// Round 8
// 682.050 us; speedup vs baseline: 1.0988x; 1.0988x over previous
//
#include <hip/hip_runtime.h>
#include <hip/hip_bf16.h>

#define NN 2048
#define BB 8
#define NC 64

typedef __bf16 bf16_8 __attribute__((ext_vector_type(8)));
typedef __bf16 bf16_4 __attribute__((ext_vector_type(4)));
typedef float f32x16 __attribute__((ext_vector_type(16)));

__device__ __forceinline__ void gll16(const void* g, void* l) {
  __builtin_amdgcn_global_load_lds((const __attribute__((address_space(1))) void*)g,
                                   (__attribute__((address_space(3))) void*)l,
                                   16, 0, 0);
}

// fp32 -> bf16 convert + transpose, 16B/lane global reads.
__global__ __launch_bounds__(256)
void k_convert(const float* __restrict__ A, __bf16* __restrict__ Ab, __bf16* __restrict__ At) {
  __shared__ __bf16 tile[64][65];
  int b = blockIdx.z;
  const float* Asrc = A + (size_t)b * NN * NN;
  __bf16* Abd = Ab + (size_t)b * NN * NN;
  __bf16* Atd = At + (size_t)b * NN * NN;
  int r0 = blockIdx.y * 64, c0 = blockIdx.x * 64;
  int row = threadIdx.x >> 4;          // 0..15
  int col4 = (threadIdx.x & 15) * 4;   // 0..60
#pragma unroll
  for (int rr = 0; rr < 64; rr += 16) {
    float4 v = *(const float4*)&Asrc[(size_t)(r0 + row + rr) * NN + c0 + col4];
    bf16_4 hv;
    hv[0] = (__bf16)v.x; hv[1] = (__bf16)v.y; hv[2] = (__bf16)v.z; hv[3] = (__bf16)v.w;
    *(bf16_4*)&Abd[(size_t)(r0 + row + rr) * NN + c0 + col4] = hv;
    tile[row + rr][col4 + 0] = hv[0];
    tile[row + rr][col4 + 1] = hv[1];
    tile[row + rr][col4 + 2] = hv[2];
    tile[row + rr][col4 + 3] = hv[3];
  }
  __syncthreads();
  int row2 = threadIdx.x >> 3;         // 0..31
  int col8 = (threadIdx.x & 7) * 8;    // 0..56
#pragma unroll
  for (int rr = 0; rr < 64; rr += 32) {
    bf16_8 v;
#pragma unroll
    for (int j = 0; j < 8; ++j) v[j] = tile[col8 + j][row2 + rr];
    *(bf16_8*)&Atd[(size_t)(c0 + row2 + rr) * NN + r0 + col8] = v;
  }
}

// C[m,n] = sum_k P[m,k]*Q[n,k] for one batch. Block 256(M)x128(N), BK=64,
// 32x32x16 MFMA, 4 waves each 128x64 (4x2 frags), XOR chunk swizzle.
// Optional dual-write epilogue (Ct != null): restage C^T through dead LDS.
__device__ __forceinline__
void gemm_body(const __bf16* __restrict__ Pb, const __bf16* __restrict__ Qb,
               __bf16* __restrict__ Cb, __bf16* __restrict__ Ctb,
               __bf16* smem, int tmBlk, int tnBlk) {
  __bf16 (*As)[64] = (__bf16(*)[64])smem;            // 256 rows (32 KB)
  __bf16 (*Bs)[64] = (__bf16(*)[64])(smem + 16384);  // 128 rows (16 KB)
  int tid = threadIdx.x;
  int wave = tid >> 6;
  int lane = tid & 63;
  int tm = tmBlk * 256;
  int tn = tnBlk * 128;
  int wm = (wave >> 1) * 128;   // rows [wm, wm+128): 4 frags
  int wn = (wave & 1) * 64;     // cols [wn, wn+64): 2 frags

  // staging: row r's 16B-chunk c lands at LDS position c ^ (r&7)
  int srow = lane >> 3;
  int sc = (lane & 7) ^ srow;
  int arowA = wave * 64;
  int arowB = wave * 32;
  const __bf16* pA = Pb + (size_t)(tm + arowA + srow) * NN + sc * 8;
  const __bf16* pB = Qb + (size_t)(tn + arowB + srow) * NN + sc * 8;

  int am = lane & 31;   // frag row (m or n) within 32
  int ah = lane >> 5;   // k-half

  f32x16 acc[4][2] = {};

  for (int k0 = 0; k0 < NN; k0 += 64) {
#pragma unroll
    for (int g = 0; g < 8; ++g)
      gll16(pA + (size_t)(g * 8) * NN + k0, &As[arowA + g * 8][0]);
#pragma unroll
    for (int g = 0; g < 4; ++g)
      gll16(pB + (size_t)(g * 8) * NN + k0, &Bs[arowB + g * 8][0]);
    __syncthreads();
#pragma unroll
    for (int ks = 0; ks < 4; ++ks) {
      int cch = ks * 2 + ah;
      bf16_8 af[4], bf2[2];
#pragma unroll
      for (int i = 0; i < 4; ++i) {
        int ra = wm + i * 32 + am;
        af[i] = *(const bf16_8*)&As[ra][(cch ^ (ra & 7)) * 8];
      }
#pragma unroll
      for (int i = 0; i < 2; ++i) {
        int rb2 = wn + i * 32 + am;
        bf2[i] = *(const bf16_8*)&Bs[rb2][(cch ^ (rb2 & 7)) * 8];
      }
#pragma unroll
      for (int im = 0; im < 4; ++im)
#pragma unroll
        for (int in = 0; in < 2; ++in)
          acc[im][in] = __builtin_amdgcn_mfma_f32_32x32x16_bf16(af[im], bf2[in], acc[im][in], 0, 0, 0);
    }
    __syncthreads();
  }

  // C/D layout (32x32): col = lane&31, row = (reg&3) + 8*(reg>>2) + 4*(lane>>5)
  int cc = lane & 31;
  int rq = (lane >> 5) * 4;
#pragma unroll
  for (int im = 0; im < 4; ++im)
#pragma unroll
    for (int in = 0; in < 2; ++in)
#pragma unroll
      for (int reg = 0; reg < 16; ++reg) {
        int row = (reg & 3) + 8 * (reg >> 2) + rq;
        Cb[(size_t)(tm + wm + im * 32 + row) * NN + (tn + wn + in * 32 + cc)] =
            (__bf16)acc[im][in][reg];
      }

  if (Ctb != nullptr) {
    __bf16 (*Tt)[258] = (__bf16(*)[258])smem;  // 64 x 258 = 33 KB < 48 KB
#pragma unroll
    for (int ch = 0; ch < 2; ++ch) {
      __syncthreads();  // smem free (K-loop / previous chunk done)
      if ((wave & 1) == ch) {
#pragma unroll
        for (int im = 0; im < 4; ++im)
#pragma unroll
          for (int in = 0; in < 2; ++in)
#pragma unroll
            for (int g = 0; g < 4; ++g) {
              bf16_4 v;
#pragma unroll
              for (int r = 0; r < 4; ++r) v[r] = (__bf16)acc[im][in][g * 4 + r];
              *(bf16_4*)&Tt[in * 32 + cc][wm + im * 32 + rq + 8 * g] = v;
            }
      }
      __syncthreads();
#pragma unroll
      for (int p = 0; p < 4; ++p) {
        int trow = p * 16 + (tid >> 4);
        int tcol = (tid & 15) * 16;
        bf16_8 v0 = *(const bf16_8*)&Tt[trow][tcol];
        bf16_8 v1 = *(const bf16_8*)&Tt[trow][tcol + 8];
        size_t gr = (size_t)(tn + ch * 64 + trow) * NN + tm + tcol;
        *(bf16_8*)&Ctb[gr] = v0;
        *(bf16_8*)&Ctb[gr + 8] = v1;
      }
    }
  }
}

// G1: A2 = A @ A (dual-write A2, A2t). Grid 1024 blocks: exact 2 passes at
// 2 blocks/CU (512 slots) — (256,3) measured WORSE here (1024/768 ragged).
__global__ __launch_bounds__(256, 2)
void k_gemm1(const __bf16* __restrict__ Ab, const __bf16* __restrict__ At,
             __bf16* __restrict__ A2, __bf16* __restrict__ A2t) {
  __shared__ __align__(16) __bf16 smem[24576];  // 48 KB
  size_t mb = (size_t)blockIdx.z * NN * NN;
  gemm_body(Ab + mb, At + mb, A2 + mb, A2t + mb, smem, blockIdx.y, blockIdx.x);
}

// G2+G3 merged: z<8 -> A3t = At @ A2^T (single write); z>=8 -> A4 = A2 @ A2
// (dual-write A4, A4t). 2048 blocks is ragged either way; 3 blocks/CU
// measured faster (314 vs 360 µs).
__global__ __launch_bounds__(256, 3)
void k_gemm23(const __bf16* __restrict__ At, const __bf16* __restrict__ A2,
              const __bf16* __restrict__ A2t,
              __bf16* __restrict__ A3t, __bf16* __restrict__ A4,
              __bf16* __restrict__ A4t) {
  __shared__ __align__(16) __bf16 smem[24576];  // 48 KB
  int job = blockIdx.z >> 3;
  size_t mb = (size_t)(blockIdx.z & 7) * NN * NN;
  if (job == 0)
    gemm_body(At + mb, A2 + mb, A3t + mb, nullptr, smem, blockIdx.y, blockIdx.x);
  else
    gemm_body(A2 + mb, A2t + mb, A4 + mb, A4t + mb, smem, blockIdx.y, blockIdx.x);
}

// One wave per row n. 4 streams: d5=row(A2)·row(A3t) (A2·A3=A^5),
// d6=row(A2)·row(A4t) (A2·A4=A^6), d7=row(A4)·row(A3t) (A4·A3=A^7),
// d8=row(A4)·row(A4t). d1..d4 are free diagonal reads.
__global__ __launch_bounds__(256)
void k_reduce(const float* __restrict__ A, const float* __restrict__ h,
              const __bf16* __restrict__ A2, const __bf16* __restrict__ A3t,
              const __bf16* __restrict__ A4, const __bf16* __restrict__ A4t,
              float* __restrict__ out) {
  int b = blockIdx.y;
  int wave = threadIdx.x >> 6, lane = threadIdx.x & 63;
  int n = blockIdx.x * 4 + wave;
  size_t mb = (size_t)b * NN * NN;
  size_t rb = mb + (size_t)n * NN;
  float d5 = 0, d6 = 0, d7 = 0, d8 = 0;
  for (int c = 0; c < NN; c += 512) {
    int k = c + lane * 8;
    bf16_8 va2  = *(const bf16_8*)(A2 + rb + k);
    bf16_8 va3t = *(const bf16_8*)(A3t + rb + k);
    bf16_8 va4  = *(const bf16_8*)(A4 + rb + k);
    bf16_8 va4t = *(const bf16_8*)(A4t + rb + k);
#pragma unroll
    for (int j = 0; j < 8; ++j) {
      float f2 = (float)va2[j], f4 = (float)va4[j];
      float f3t = (float)va3t[j], f4t = (float)va4t[j];
      d5 += f2 * f3t;
      d6 += f2 * f4t;
      d7 += f4 * f3t;
      d8 += f4 * f4t;
    }
  }
#pragma unroll
  for (int off = 32; off > 0; off >>= 1) {
    d5 += __shfl_xor(d5, off);
    d6 += __shfl_xor(d6, off);
    d7 += __shfl_xor(d7, off);
    d8 += __shfl_xor(d8, off);
  }
  float d1 = A[mb + (size_t)n * NN + n];
  float d2 = (float)A2[rb + n];
  float d3 = (float)A3t[rb + n];
  float d4 = (float)A4[rb + n];
  // lane == channel (NC=64)
  float r = h[lane] + h[64 + lane] * d1 + h[128 + lane] * d2 + h[192 + lane] * d3 +
            h[256 + lane] * d4 + h[320 + lane] * d5 + h[384 + lane] * d6 +
            h[448 + lane] * d7 + h[512 + lane] * d8;
  out[((size_t)b * NN + n) * NC + lane] = r;
}

extern "C" void kernel_launch(void* const* d_in, const int* in_sizes, int n_in,
                              void* d_out, int out_size, void* d_ws, size_t ws_size,
                              hipStream_t stream) {
  const float* A = (const float*)d_in[0];
  const float* h = (const float*)d_in[1];
  float* out = (float*)d_out;

  size_t elems = (size_t)BB * NN * NN;  // 64 MiB per bf16 buffer
  __bf16* Ab  = (__bf16*)d_ws;
  __bf16* At  = Ab + elems;
  __bf16* A2  = At + elems;
  __bf16* A2t = A2 + elems;
  __bf16* A3t = A2t + elems;
  __bf16* A4  = A3t + elems;
  __bf16* A4t = Ab;  // alias: Ab dead after G1 (total ws: 6 x 64 MiB)

  dim3 bl(256);
  // A -> bf16 + transpose
  k_convert<<<dim3(32, 32, BB), bl, 0, stream>>>(A, Ab, At);
  // A2 = A @ A  (dual-write)
  k_gemm1<<<dim3(16, 8, BB), bl, 0, stream>>>(Ab, At, A2, A2t);
  // A3t = (A^3)^T and A4 = A2 @ A2 (+A4t) in one dispatch
  k_gemm23<<<dim3(16, 8, 2 * BB), bl, 0, stream>>>(At, A2, A2t, A3t, A4, A4t);
  // diagonals + channel combine
  k_reduce<<<dim3(NN / 4, BB), bl, 0, stream>>>(A, h, A2, A3t, A4, A4t, out);
}